// Round 11
// baseline (221.925 us; speedup 1.0000x reference)
//
#include <hip/hip_runtime.h>

// ---------------------------------------------------------------------------
// sLSTM cell, B=8192, D=1024, H=1024.
//   pre[B,4H] = [x,h_prev] @ [Wg|Rg]^T  (K = D+H = 2048)
//   i=exp(pi+bi), f=sig(pf+bf), o=sig(po+bo), z=tanh(pz+bz)
//   c=f*c_prev+i*z ; n=f*n_prev+i ; m=max(log f + m_prev, pi) ; h=o*c/n
//   outputs (flat): h, c, C_prev(copy), n, m  -- each B*H f32
//
// Round 11 = R10 with the epilogue operands moved from LDS panels to
// REGISTERS, issued early under the last K-tile's staging drain:
//   - Last K-tile peeled. The 48 statically-indexed scalar loads of
//     c/n/m_prev (+4 bias loads) are issued between the peeled stage-issue
//     and its __syncthreads(): the barrier's vmcnt(0) drain (~900cy, paid
//     anyway for the staging loads) covers their latency for free.
//   - Epilogue computes from registers: no LDS panels (back to 32KB), no
//     bank conflicts, no post-loop vmcnt exposure.
//   - Trailing __syncthreads() after the last MFMA deleted (no LDS consumer
//     follows) -- waves retire independently, shrinking the block tail.
//   - VGPR +48, but R10 was already past the 128-unified-register bin, so
//     the occupancy bin is unchanged (~2-2.3 waves/SIMD).
// K-loop body, grid, convert kernel identical to R9/R10.
// Gate-interleaved W packing: packed row r -> gate (r>>4)&3,
// j=(r>>6)*16+(r&15) => a wave's 4 N-frags are {pi,pf,po,pz} of the same j.
// ---------------------------------------------------------------------------

#define B_SZ 8192
#define D_SZ 1024
#define H_SZ 1024
#define K_SZ 2048   // D + H
#define N4H  4096   // 4*H

typedef __attribute__((ext_vector_type(4))) float f32x4;
typedef _Float16 f16;
typedef __attribute__((ext_vector_type(8))) f16 f16x8;
typedef unsigned short u16;
typedef __attribute__((ext_vector_type(4))) unsigned short u16x4;

static __device__ __forceinline__ u16 f2h(float f) {
    f16 h = (f16)f;
    return __builtin_bit_cast(unsigned short, h);
}

static __device__ __forceinline__ float rcp_fast(float x) {
    float r;
    asm("v_rcp_f32 %0, %1" : "=v"(r) : "v"(x));
    return r;
}

static __device__ __forceinline__ void load_lds16(const void* g, void* l) {
    __builtin_amdgcn_global_load_lds(
        (const __attribute__((address_space(1))) void*)g,
        (__attribute__((address_space(3))) void*)l, 16, 0, 0);
}

// ---------------------------------------------------------------------------
// Merged pack + passthrough kernel (identical to R9/R10).
// ---------------------------------------------------------------------------
__global__ void convert_AW(const float* __restrict__ x, const float* __restrict__ h,
                           const float* __restrict__ Wi, const float* __restrict__ Wf,
                           const float* __restrict__ Wo, const float* __restrict__ Wz,
                           const float* __restrict__ Ri, const float* __restrict__ Rf,
                           const float* __restrict__ Ro, const float* __restrict__ Rz,
                           const float* __restrict__ C_prev,
                           u16* __restrict__ A, u16* __restrict__ Wb,
                           float* __restrict__ outC) {
    const size_t nvecA = (size_t)B_SZ * K_SZ / 4;
    const size_t nvecW = (size_t)N4H * K_SZ / 4;
    const size_t nvecC = (size_t)B_SZ * H_SZ / 4;
    const size_t nvec  = nvecA + nvecW + nvecC;
    const size_t stride = (size_t)gridDim.x * blockDim.x;
    for (size_t v = (size_t)blockIdx.x * blockDim.x + threadIdx.x; v < nvec; v += stride) {
        if (v >= nvecA + nvecW) {
            size_t e = (v - nvecA - nvecW) * 4;
            *(f32x4*)&outC[e] = *(const f32x4*)&C_prev[e];
            continue;
        }
        const float* src;
        u16* dst;
        if (v < nvecA) {
            size_t e = v * 4;
            size_t row = e >> 11;
            int col = (int)(e & 2047);
            src = (col < D_SZ) ? (x + row * D_SZ + col)
                               : (h + row * H_SZ + (col - D_SZ));
            dst = A + e;
        } else {
            size_t e = (v - nvecA) * 4;
            size_t r = e >> 11;                 // packed row 0..4095
            int col = (int)(e & 2047);
            int g = (int)(r >> 4) & 3;          // gate
            int j = (int)((r >> 6) << 4) | (int)(r & 15);
            const float* Wg = (g == 0) ? Wi : (g == 1) ? Wf : (g == 2) ? Wo : Wz;
            const float* Rg = (g == 0) ? Ri : (g == 1) ? Rf : (g == 2) ? Ro : Rz;
            src = (col < D_SZ) ? (Wg + (size_t)j * D_SZ + col)
                               : (Rg + (size_t)j * H_SZ + (col - D_SZ));
            dst = Wb + e;
        }
        f32x4 val = *(const f32x4*)src;
        u16x4 o;
        o[0] = f2h(val[0]); o[1] = f2h(val[1]); o[2] = f2h(val[2]); o[3] = f2h(val[3]);
        *(u16x4*)dst = o;
    }
}

// ---------------------------------------------------------------------------
// Fused GEMM + sLSTM epilogue. 256 threads, 4 waves, 128x128 tile, BK=64.
// K-loop identical to R2/R9/R10; last tile peeled for early operand loads.
// ---------------------------------------------------------------------------
__global__ __launch_bounds__(256, 2)
void gemm_fused(const u16* __restrict__ A, const u16* __restrict__ W,
                const float* __restrict__ c_prev, const float* __restrict__ n_prev,
                const float* __restrict__ m_prev,
                const float* __restrict__ bi, const float* __restrict__ bfv,
                const float* __restrict__ bo, const float* __restrict__ bz,
                float* __restrict__ out) {
    __shared__ u16 lA[128 * 64];   // 16 KB
    __shared__ u16 lB[128 * 64];   // 16 KB

    const int tid = threadIdx.x;
    const int w  = tid >> 6;       // wave 0..3
    const int l  = tid & 63;       // lane
    const int wm = w >> 1;         // wave row (2)
    const int wn = w & 1;          // wave col (2)
    const int m0 = blockIdx.x * 128;
    const int n0 = blockIdx.y * 128;

    const int lrow8 = l >> 3;            // row within the wave's 8-row stripe
    const int lseg  = (l & 7) ^ lrow8;   // pre-swizzled global 16B-segment index

    const int fr = l & 15;   // fragment row (M for A, N for B), also C col
    const int kq = l >> 4;   // k-quad 0..3

    f32x4 acc[4][4] = {};

    auto stage = [&](int kt) {
#pragma unroll
        for (int r = 0; r < 4; ++r) {
            int rowA = r * 32 + w * 8 + lrow8;               // 0..127
            const u16* gA = A + (size_t)(m0 + rowA) * K_SZ + kt + lseg * 8;
            load_lds16(gA, (char*)lA + (r * 32 + w * 8) * 128);
            const u16* gB = W + (size_t)(n0 + rowA) * K_SZ + kt + lseg * 8;
            load_lds16(gB, (char*)lB + (r * 32 + w * 8) * 128);
        }
    };

    auto compute = [&]() {
#pragma unroll
        for (int ks = 0; ks < 2; ++ks) {
            f16x8 af[4], bfr[4];
#pragma unroll
            for (int mi = 0; mi < 4; ++mi) {
                int row = wm * 64 + mi * 16 + fr;
                int seg = (ks * 4 + kq) ^ (row & 7);
                af[mi] = *(const f16x8*)&lA[row * 64 + seg * 8];
            }
#pragma unroll
            for (int ni = 0; ni < 4; ++ni) {
                int row = wn * 64 + ni * 16 + fr;
                int seg = (ks * 4 + kq) ^ (row & 7);
                bfr[ni] = *(const f16x8*)&lB[row * 64 + seg * 8];
            }
#pragma unroll
            for (int mi = 0; mi < 4; ++mi)
#pragma unroll
                for (int ni = 0; ni < 4; ++ni)
                    acc[mi][ni] = __builtin_amdgcn_mfma_f32_16x16x32_f16(
                        af[mi], bfr[ni], acc[mi][ni], 0, 0, 0);
        }
    };

    // ---- main K-loop, last tile peeled -----------------------------------
    for (int kt = 0; kt < K_SZ - 64; kt += 64) {
        stage(kt);
        __syncthreads();
        compute();
        __syncthreads();
    }

    stage(K_SZ - 64);

    // ---- epilogue operand prefetch (registers), issued under the barrier's
    // vmcnt(0) drain of the staging loads above: latency is free ----------
    const size_t BH = (size_t)B_SZ * H_SZ;
    const int j = ((n0 + wn * 64) >> 6) * 16 + fr;    // 0..1023
    float cp[4][4], np[4][4], mp[4][4];
#pragma unroll
    for (int mi = 0; mi < 4; ++mi) {
        const int rbase = m0 + wm * 64 + mi * 16 + kq * 4;
#pragma unroll
        for (int r2 = 0; r2 < 4; ++r2) {
            const size_t idx = (size_t)(rbase + r2) * H_SZ + j;
            cp[mi][r2] = c_prev[idx];
            np[mi][r2] = n_prev[idx];
            mp[mi][r2] = m_prev[idx];
        }
    }
    const float bvi = bi[j], bvf = bfv[j], bvo = bo[j], bvz = bz[j];

    __syncthreads();           // staging + prefetch drained together
    compute();                 // last K-tile
    // no trailing barrier: no LDS consumer follows; waves retire freely.

    // ---- fused sLSTM epilogue (fully register-resident) ------------------
#pragma unroll
    for (int mi = 0; mi < 4; ++mi) {
        const int rbase = m0 + wm * 64 + mi * 16 + kq * 4;
#pragma unroll
        for (int r2 = 0; r2 < 4; ++r2) {
            const size_t idx = (size_t)(rbase + r2) * H_SZ + j;
            float pi = acc[mi][0][r2] + bvi;
            float pf = acc[mi][1][r2] + bvf;
            float po = acc[mi][2][r2] + bvo;
            float pz = acc[mi][3][r2] + bvz;
            float iv = __expf(pi);
            float fv = rcp_fast(1.0f + __expf(-pf));                   // sigmoid
            float ov = rcp_fast(1.0f + __expf(-po));                   // sigmoid
            float zv = 1.0f - 2.0f * rcp_fast(__expf(2.0f * pz) + 1.0f); // tanh
            float cv = fv * cp[mi][r2] + iv * zv;
            float nv = fv * np[mi][r2] + iv;
            float mv = fmaxf(__logf(fv) + mp[mi][r2], pi);
            out[idx]          = ov * cv * rcp_fast(nv);                // h
            out[BH + idx]     = cv;                                    // c
            out[3 * BH + idx] = nv;                                    // n
            out[4 * BH + idx] = mv;                                    // m
        }
    }
}

// ---------------------------------------------------------------------------
extern "C" void kernel_launch(void* const* d_in, const int* in_sizes, int n_in,
                              void* d_out, int out_size, void* d_ws, size_t ws_size,
                              hipStream_t stream) {
    const float* x      = (const float*)d_in[0];
    const float* h_prev = (const float*)d_in[1];
    const float* c_prev = (const float*)d_in[2];
    const float* C_prev = (const float*)d_in[3];
    const float* n_prev = (const float*)d_in[4];
    const float* m_prev = (const float*)d_in[5];
    const float* Wz = (const float*)d_in[6];
    const float* bz = (const float*)d_in[7];
    const float* Rz = (const float*)d_in[8];
    const float* Wi = (const float*)d_in[9];
    const float* bi = (const float*)d_in[10];
    const float* Ri = (const float*)d_in[11];
    const float* Wf = (const float*)d_in[12];
    const float* bf = (const float*)d_in[13];
    const float* Rf = (const float*)d_in[14];
    const float* Wo = (const float*)d_in[15];
    const float* bo = (const float*)d_in[16];
    const float* Ro = (const float*)d_in[17];
    float* out = (float*)d_out;

    const size_t BH = (size_t)B_SZ * H_SZ;

    // workspace layout: A_f16 (32MB) | W_f16 (16MB)
    u16* Abuf = (u16*)d_ws;
    u16* Wbuf = (u16*)((char*)d_ws + (size_t)32 * 1024 * 1024);

    convert_AW<<<2048, 256, 0, stream>>>(x, h_prev, Wi, Wf, Wo, Wz,
                                         Ri, Rf, Ro, Rz, C_prev,
                                         Abuf, Wbuf, out + 2 * BH);

    gemm_fused<<<dim3(B_SZ / 128, N4H / 128), 256, 0, stream>>>(
        Abuf, Wbuf, c_prev, n_prev, m_prev, bi, bf, bo, bz, out);
}

// Round 12
// 220.994 us; speedup vs baseline: 1.0042x; 1.0042x over previous
//
#include <hip/hip_runtime.h>

// ---------------------------------------------------------------------------
// sLSTM cell, B=8192, D=1024, H=1024.
//   pre[B,4H] = [x,h_prev] @ [Wg|Rg]^T  (K = D+H = 2048)
//   i=exp(pi+bi), f=sig(pf+bf), o=sig(po+bo), z=tanh(pz+bz)
//   c=f*c_prev+i*z ; n=f*n_prev+i ; m=max(log f + m_prev, pi) ; h=o*c/n
//   outputs (flat): h, c, C_prev(copy), n, m  -- each B*H f32
//
// Round 12: occupancy attack via smaller per-wave tile.
//   128x128 block tile, BK=64, but 8 waves (4M x 2N) of 32x64 each:
//   acc = 2x4 frags = 32 AGPR (vs 64). Unified regs ~80-90 -> 5-6 waves/SIMD
//   bin (vs 3 at R10's 132). Same chip-wide MFMA count; 2x the TLP to hide
//   the per-tile vmcnt(0) barrier drains (the mechanism that made R2/R9 the
//   best structures). LDS 32KB. Lane-local gate-interleaved epilogue
//   unchanged (N-wave width still 64 packed cols); per-lane epilogue work
//   halves. Epilogue operands inline-loaded (TLP hides them at this
//   occupancy; avoids R10's +4 / R11's +40 VGPR).
// Gate-interleaved W packing: packed row r -> gate (r>>4)&3,
// j=(r>>6)*16+(r&15) => a wave's 4 N-frags are {pi,pf,po,pz} of the same j.
// ---------------------------------------------------------------------------

#define B_SZ 8192
#define D_SZ 1024
#define H_SZ 1024
#define K_SZ 2048   // D + H
#define N4H  4096   // 4*H

typedef __attribute__((ext_vector_type(4))) float f32x4;
typedef _Float16 f16;
typedef __attribute__((ext_vector_type(8))) f16 f16x8;
typedef unsigned short u16;
typedef __attribute__((ext_vector_type(4))) unsigned short u16x4;

static __device__ __forceinline__ u16 f2h(float f) {
    f16 h = (f16)f;
    return __builtin_bit_cast(unsigned short, h);
}

static __device__ __forceinline__ float rcp_fast(float x) {
    float r;
    asm("v_rcp_f32 %0, %1" : "=v"(r) : "v"(x));
    return r;
}

static __device__ __forceinline__ void load_lds16(const void* g, void* l) {
    __builtin_amdgcn_global_load_lds(
        (const __attribute__((address_space(1))) void*)g,
        (__attribute__((address_space(3))) void*)l, 16, 0, 0);
}

// ---------------------------------------------------------------------------
// Merged pack + passthrough kernel (identical to R9/R10).
// ---------------------------------------------------------------------------
__global__ void convert_AW(const float* __restrict__ x, const float* __restrict__ h,
                           const float* __restrict__ Wi, const float* __restrict__ Wf,
                           const float* __restrict__ Wo, const float* __restrict__ Wz,
                           const float* __restrict__ Ri, const float* __restrict__ Rf,
                           const float* __restrict__ Ro, const float* __restrict__ Rz,
                           const float* __restrict__ C_prev,
                           u16* __restrict__ A, u16* __restrict__ Wb,
                           float* __restrict__ outC) {
    const size_t nvecA = (size_t)B_SZ * K_SZ / 4;
    const size_t nvecW = (size_t)N4H * K_SZ / 4;
    const size_t nvecC = (size_t)B_SZ * H_SZ / 4;
    const size_t nvec  = nvecA + nvecW + nvecC;
    const size_t stride = (size_t)gridDim.x * blockDim.x;
    for (size_t v = (size_t)blockIdx.x * blockDim.x + threadIdx.x; v < nvec; v += stride) {
        if (v >= nvecA + nvecW) {
            size_t e = (v - nvecA - nvecW) * 4;
            *(f32x4*)&outC[e] = *(const f32x4*)&C_prev[e];
            continue;
        }
        const float* src;
        u16* dst;
        if (v < nvecA) {
            size_t e = v * 4;
            size_t row = e >> 11;
            int col = (int)(e & 2047);
            src = (col < D_SZ) ? (x + row * D_SZ + col)
                               : (h + row * H_SZ + (col - D_SZ));
            dst = A + e;
        } else {
            size_t e = (v - nvecA) * 4;
            size_t r = e >> 11;                 // packed row 0..4095
            int col = (int)(e & 2047);
            int g = (int)(r >> 4) & 3;          // gate
            int j = (int)((r >> 6) << 4) | (int)(r & 15);
            const float* Wg = (g == 0) ? Wi : (g == 1) ? Wf : (g == 2) ? Wo : Wz;
            const float* Rg = (g == 0) ? Ri : (g == 1) ? Rf : (g == 2) ? Ro : Rz;
            src = (col < D_SZ) ? (Wg + (size_t)j * D_SZ + col)
                               : (Rg + (size_t)j * H_SZ + (col - D_SZ));
            dst = Wb + e;
        }
        f32x4 val = *(const f32x4*)src;
        u16x4 o;
        o[0] = f2h(val[0]); o[1] = f2h(val[1]); o[2] = f2h(val[2]); o[3] = f2h(val[3]);
        *(u16x4*)dst = o;
    }
}

// ---------------------------------------------------------------------------
// Fused GEMM + sLSTM epilogue. 512 threads, 8 waves (4M x 2N), 128x128 tile,
// BK=64, per-wave 32x64, acc 2x4 (32 AGPR). R2-style 2-barrier K-loop.
// ---------------------------------------------------------------------------
__global__ __launch_bounds__(512, 4)
void gemm_fused(const u16* __restrict__ A, const u16* __restrict__ W,
                const float* __restrict__ c_prev, const float* __restrict__ n_prev,
                const float* __restrict__ m_prev,
                const float* __restrict__ bi, const float* __restrict__ bfv,
                const float* __restrict__ bo, const float* __restrict__ bz,
                float* __restrict__ out) {
    __shared__ u16 lA[128 * 64];   // 16 KB
    __shared__ u16 lB[128 * 64];   // 16 KB

    const int tid = threadIdx.x;
    const int w  = tid >> 6;       // wave 0..7
    const int l  = tid & 63;       // lane
    const int wm = w >> 1;         // M-wave 0..3 (32 rows each)
    const int wn = w & 1;          // N-wave 0..1 (64 packed cols each)
    const int m0 = blockIdx.x * 128;
    const int n0 = blockIdx.y * 128;

    const int lrow8 = l >> 3;            // row within the wave's 8-row stripe
    const int lseg  = (l & 7) ^ lrow8;   // pre-swizzled global 16B-segment index

    const int fr = l & 15;   // fragment row (M for A, N for B), also C col
    const int kq = l >> 4;   // k-quad 0..3

    f32x4 acc[2][4] = {};

    for (int kt = 0; kt < K_SZ; kt += 64) {
        // ---- stage: 2 rounds x (A,B); 8 waves cover 128 rows/round -------
#pragma unroll
        for (int r = 0; r < 2; ++r) {
            int rowA = r * 64 + w * 8 + lrow8;               // 0..127
            const u16* gA = A + (size_t)(m0 + rowA) * K_SZ + kt + lseg * 8;
            load_lds16(gA, (char*)lA + (r * 64 + w * 8) * 128);
            const u16* gB = W + (size_t)(n0 + rowA) * K_SZ + kt + lseg * 8;
            load_lds16(gB, (char*)lB + (r * 64 + w * 8) * 128);
        }
        __syncthreads();

        // ---- compute: 2 k-slices of 32, 2x4 frags ------------------------
#pragma unroll
        for (int ks = 0; ks < 2; ++ks) {
            f16x8 af[2], bfr[4];
#pragma unroll
            for (int mi = 0; mi < 2; ++mi) {
                int row = wm * 32 + mi * 16 + fr;
                int seg = (ks * 4 + kq) ^ (row & 7);
                af[mi] = *(const f16x8*)&lA[row * 64 + seg * 8];
            }
#pragma unroll
            for (int ni = 0; ni < 4; ++ni) {
                int row = wn * 64 + ni * 16 + fr;
                int seg = (ks * 4 + kq) ^ (row & 7);
                bfr[ni] = *(const f16x8*)&lB[row * 64 + seg * 8];
            }
#pragma unroll
            for (int mi = 0; mi < 2; ++mi)
#pragma unroll
                for (int ni = 0; ni < 4; ++ni)
                    acc[mi][ni] = __builtin_amdgcn_mfma_f32_16x16x32_f16(
                        af[mi], bfr[ni], acc[mi][ni], 0, 0, 0);
        }
        __syncthreads();
    }

    // ---- fused sLSTM epilogue (fully lane-local) -------------------------
    const size_t BH = (size_t)B_SZ * H_SZ;
    const int j = ((n0 + wn * 64) >> 6) * 16 + fr;    // 0..1023
    const float bvi = bi[j], bvf = bfv[j], bvo = bo[j], bvz = bz[j];

#pragma unroll
    for (int mi = 0; mi < 2; ++mi) {
        const int rbase = m0 + wm * 32 + mi * 16 + kq * 4;
#pragma unroll
        for (int r2 = 0; r2 < 4; ++r2) {
            const size_t idx = (size_t)(rbase + r2) * H_SZ + j;
            float pi = acc[mi][0][r2] + bvi;
            float pf = acc[mi][1][r2] + bvf;
            float po = acc[mi][2][r2] + bvo;
            float pz = acc[mi][3][r2] + bvz;
            float iv = __expf(pi);
            float fv = rcp_fast(1.0f + __expf(-pf));                     // sigmoid
            float ov = rcp_fast(1.0f + __expf(-po));                     // sigmoid
            float zv = 1.0f - 2.0f * rcp_fast(__expf(2.0f * pz) + 1.0f); // tanh
            float cv = fv * c_prev[idx] + iv * zv;
            float nv = fv * n_prev[idx] + iv;
            float mv = fmaxf(__logf(fv) + m_prev[idx], pi);
            out[idx]          = ov * cv * rcp_fast(nv);                  // h
            out[BH + idx]     = cv;                                      // c
            out[3 * BH + idx] = nv;                                      // n
            out[4 * BH + idx] = mv;                                      // m
        }
    }
}

// ---------------------------------------------------------------------------
extern "C" void kernel_launch(void* const* d_in, const int* in_sizes, int n_in,
                              void* d_out, int out_size, void* d_ws, size_t ws_size,
                              hipStream_t stream) {
    const float* x      = (const float*)d_in[0];
    const float* h_prev = (const float*)d_in[1];
    const float* c_prev = (const float*)d_in[2];
    const float* C_prev = (const float*)d_in[3];
    const float* n_prev = (const float*)d_in[4];
    const float* m_prev = (const float*)d_in[5];
    const float* Wz = (const float*)d_in[6];
    const float* bz = (const float*)d_in[7];
    const float* Rz = (const float*)d_in[8];
    const float* Wi = (const float*)d_in[9];
    const float* bi = (const float*)d_in[10];
    const float* Ri = (const float*)d_in[11];
    const float* Wf = (const float*)d_in[12];
    const float* bf = (const float*)d_in[13];
    const float* Rf = (const float*)d_in[14];
    const float* Wo = (const float*)d_in[15];
    const float* bo = (const float*)d_in[16];
    const float* Ro = (const float*)d_in[17];
    float* out = (float*)d_out;

    const size_t BH = (size_t)B_SZ * H_SZ;

    // workspace layout: A_f16 (32MB) | W_f16 (16MB)
    u16* Abuf = (u16*)d_ws;
    u16* Wbuf = (u16*)((char*)d_ws + (size_t)32 * 1024 * 1024);

    convert_AW<<<2048, 256, 0, stream>>>(x, h_prev, Wi, Wf, Wo, Wz,
                                         Ri, Rf, Ro, Rz, C_prev,
                                         Abuf, Wbuf, out + 2 * BH);

    gemm_fused<<<dim3(B_SZ / 128, N4H / 128), 512, 0, stream>>>(
        Abuf, Wbuf, c_prev, n_prev, m_prev, bi, bf, bo, bz, out);
}

// Round 13
// 208.543 us; speedup vs baseline: 1.0642x; 1.0597x over previous
//
#include <hip/hip_runtime.h>

// ---------------------------------------------------------------------------
// sLSTM cell, B=8192, D=1024, H=1024.
//   pre[B,4H] = [x,h_prev] @ [Wg|Rg]^T  (K = D+H = 2048)
//   i=exp(pi+bi), f=sig(pf+bf), o=sig(po+bo), z=tanh(pz+bz)
//   c=f*c_prev+i*z ; n=f*n_prev+i ; m=max(log f + m_prev, pi) ; h=o*c/n
//   outputs (flat): h, c, C_prev(copy), n, m  -- each B*H f32
//
// Round 13 = R10 (measured best: 210.4us total, gemm 180us) + one latency
// hide: the last K-tile is peeled, and the m_prev panel (whose LDS region --
// the extra 16KB -- never aliases the K-loop tiles) plus the 4 bias loads
// are issued BEFORE the last-tile barrier, so their ~900cy ride the
// barrier's existing staging drain for free. Post-loop exposure shrinks
// from 12 gload_lds to 8 (c/n panels, which overlay lA/lB and cannot move).
//   - K-loop body, grid, tile geometry, convert kernel: identical to R10.
//   - Epilogue: LDS panels (c/n post-loop, m early), rcp_fast math.
//   - VGPR +4 (bias regs across barrier): same occupancy bin
//     (floor(512/136)=3 waves/SIMD; LDS 48KB caps at 3 blocks/CU anyway).
// Gate-interleaved W packing: packed row r -> gate (r>>4)&3,
// j=(r>>6)*16+(r&15) => a wave's 4 N-frags are {pi,pf,po,pz} of the same j.
// ---------------------------------------------------------------------------

#define B_SZ 8192
#define D_SZ 1024
#define H_SZ 1024
#define K_SZ 2048   // D + H
#define N4H  4096   // 4*H

typedef __attribute__((ext_vector_type(4))) float f32x4;
typedef _Float16 f16;
typedef __attribute__((ext_vector_type(8))) f16 f16x8;
typedef unsigned short u16;
typedef __attribute__((ext_vector_type(4))) unsigned short u16x4;

static __device__ __forceinline__ u16 f2h(float f) {
    f16 h = (f16)f;
    return __builtin_bit_cast(unsigned short, h);
}

static __device__ __forceinline__ float rcp_fast(float x) {
    float r;
    asm("v_rcp_f32 %0, %1" : "=v"(r) : "v"(x));
    return r;
}

static __device__ __forceinline__ void load_lds16(const void* g, void* l) {
    __builtin_amdgcn_global_load_lds(
        (const __attribute__((address_space(1))) void*)g,
        (__attribute__((address_space(3))) void*)l, 16, 0, 0);
}

// ---------------------------------------------------------------------------
// Merged pack + passthrough kernel (identical to R9/R10).
// ---------------------------------------------------------------------------
__global__ void convert_AW(const float* __restrict__ x, const float* __restrict__ h,
                           const float* __restrict__ Wi, const float* __restrict__ Wf,
                           const float* __restrict__ Wo, const float* __restrict__ Wz,
                           const float* __restrict__ Ri, const float* __restrict__ Rf,
                           const float* __restrict__ Ro, const float* __restrict__ Rz,
                           const float* __restrict__ C_prev,
                           u16* __restrict__ A, u16* __restrict__ Wb,
                           float* __restrict__ outC) {
    const size_t nvecA = (size_t)B_SZ * K_SZ / 4;
    const size_t nvecW = (size_t)N4H * K_SZ / 4;
    const size_t nvecC = (size_t)B_SZ * H_SZ / 4;
    const size_t nvec  = nvecA + nvecW + nvecC;
    const size_t stride = (size_t)gridDim.x * blockDim.x;
    for (size_t v = (size_t)blockIdx.x * blockDim.x + threadIdx.x; v < nvec; v += stride) {
        if (v >= nvecA + nvecW) {
            size_t e = (v - nvecA - nvecW) * 4;
            *(f32x4*)&outC[e] = *(const f32x4*)&C_prev[e];
            continue;
        }
        const float* src;
        u16* dst;
        if (v < nvecA) {
            size_t e = v * 4;
            size_t row = e >> 11;
            int col = (int)(e & 2047);
            src = (col < D_SZ) ? (x + row * D_SZ + col)
                               : (h + row * H_SZ + (col - D_SZ));
            dst = A + e;
        } else {
            size_t e = (v - nvecA) * 4;
            size_t r = e >> 11;                 // packed row 0..4095
            int col = (int)(e & 2047);
            int g = (int)(r >> 4) & 3;          // gate
            int j = (int)((r >> 6) << 4) | (int)(r & 15);
            const float* Wg = (g == 0) ? Wi : (g == 1) ? Wf : (g == 2) ? Wo : Wz;
            const float* Rg = (g == 0) ? Ri : (g == 1) ? Rf : (g == 2) ? Ro : Rz;
            src = (col < D_SZ) ? (Wg + (size_t)j * D_SZ + col)
                               : (Rg + (size_t)j * H_SZ + (col - D_SZ));
            dst = Wb + e;
        }
        f32x4 val = *(const f32x4*)src;
        u16x4 o;
        o[0] = f2h(val[0]); o[1] = f2h(val[1]); o[2] = f2h(val[2]); o[3] = f2h(val[3]);
        *(u16x4*)dst = o;
    }
}

// ---------------------------------------------------------------------------
// Fused GEMM + sLSTM epilogue. 256 threads, 4 waves, 128x128 tile, BK=64.
// K-loop identical to R2/R9/R10; last tile peeled to hide m-panel + bias
// loads under its barrier drain. Epilogue operands staged to LDS.
// ---------------------------------------------------------------------------
__global__ __launch_bounds__(256, 2)
void gemm_fused(const u16* __restrict__ A, const u16* __restrict__ W,
                const float* __restrict__ c_prev, const float* __restrict__ n_prev,
                const float* __restrict__ m_prev,
                const float* __restrict__ bi, const float* __restrict__ bfv,
                const float* __restrict__ bo, const float* __restrict__ bz,
                float* __restrict__ out) {
    __shared__ char smem[49152];                 // 48KB -> 3 blocks/CU
    u16* lA = (u16*)smem;                        // 16KB (K-loop A tile)
    u16* lB = (u16*)(smem + 16384);              // 16KB (K-loop B tile)
    // epilogue overlays: c/n panels reuse lA/lB space (valid only after the
    // final K-loop barrier); m panel lives in the extra 16KB (NEVER aliases
    // the K-loop tiles, so it can be staged early).
    float* eC = (float*)smem;                    // reuses lA space
    float* eN = (float*)(smem + 16384);          // reuses lB space
    float* eM = (float*)(smem + 32768);          // extra 16KB, K-loop-free

    const int tid = threadIdx.x;
    const int w  = tid >> 6;       // wave 0..3
    const int l  = tid & 63;       // lane
    const int wm = w >> 1;         // wave row (2)
    const int wn = w & 1;          // wave col (2)
    const int m0 = blockIdx.x * 128;
    const int n0 = blockIdx.y * 128;

    const int lrow8 = l >> 3;            // row within the wave's 8-row stripe
    const int lseg  = (l & 7) ^ lrow8;   // pre-swizzled global 16B-segment index

    const int fr = l & 15;   // fragment row (M for A, N for B), also C col
    const int kq = l >> 4;   // k-quad 0..3

    f32x4 acc[4][4] = {};

    auto stage = [&](int kt) {
#pragma unroll
        for (int r = 0; r < 4; ++r) {
            int rowA = r * 32 + w * 8 + lrow8;               // 0..127
            const u16* gA = A + (size_t)(m0 + rowA) * K_SZ + kt + lseg * 8;
            load_lds16(gA, (char*)lA + (r * 32 + w * 8) * 128);
            const u16* gB = W + (size_t)(n0 + rowA) * K_SZ + kt + lseg * 8;
            load_lds16(gB, (char*)lB + (r * 32 + w * 8) * 128);
        }
    };

    auto compute = [&]() {
#pragma unroll
        for (int ks = 0; ks < 2; ++ks) {
            f16x8 af[4], bfr[4];
#pragma unroll
            for (int mi = 0; mi < 4; ++mi) {
                int row = wm * 64 + mi * 16 + fr;
                int seg = (ks * 4 + kq) ^ (row & 7);
                af[mi] = *(const f16x8*)&lA[row * 64 + seg * 8];
            }
#pragma unroll
            for (int ni = 0; ni < 4; ++ni) {
                int row = wn * 64 + ni * 16 + fr;
                int seg = (ks * 4 + kq) ^ (row & 7);
                bfr[ni] = *(const f16x8*)&lB[row * 64 + seg * 8];
            }
#pragma unroll
            for (int mi = 0; mi < 4; ++mi)
#pragma unroll
                for (int ni = 0; ni < 4; ++ni)
                    acc[mi][ni] = __builtin_amdgcn_mfma_f32_16x16x32_f16(
                        af[mi], bfr[ni], acc[mi][ni], 0, 0, 0);
        }
    };

    // epilogue panel geometry: wave (wm,wn) owns rows [m0+wm*64,+64) x cols
    // [jbase,+16).  Per issue k: lane l covers row k*16+(l>>2), 16B (l&3).
    const int jbase = ((n0 + wn * 64) >> 6) * 16;
    const size_t goff = (size_t)(m0 + wm * 64) * H_SZ + jbase;
    const size_t lsrc = (size_t)(l >> 2) * H_SZ + (l & 3) * 4;

    // ---- main K-loop, last tile peeled -----------------------------------
    for (int kt = 0; kt < K_SZ - 64; kt += 64) {
        stage(kt);
        __syncthreads();
        compute();
        __syncthreads();
    }

    // peeled last tile: stage it, then issue the m-panel (region untouched
    // by the K-loop) and bias loads -- all drained for free by the barrier.
    stage(K_SZ - 64);
    {
        const float* mb = m_prev + goff;
#pragma unroll
        for (int k = 0; k < 4; ++k)
            load_lds16(mb + (size_t)k * 16 * H_SZ + lsrc,
                       (char*)eM + w * 4096 + k * 1024);
    }
    const int j = jbase + fr;                          // 0..1023
    const float bvi = bi[j], bvf = bfv[j], bvo = bo[j], bvz = bz[j];

    __syncthreads();           // drains staging + m-panel + bias loads
    compute();                 // last K-tile
    __syncthreads();           // all waves' lA/lB reads done -> overlay free

    // ---- c/n panel prefetch into the lA/lB overlay (wave-local) ----------
    {
        const float* cb = c_prev + goff;
        const float* nb = n_prev + goff;
#pragma unroll
        for (int k = 0; k < 4; ++k) {
            load_lds16(cb + (size_t)k * 16 * H_SZ + lsrc,
                       (char*)eC + w * 4096 + k * 1024);
            load_lds16(nb + (size_t)k * 16 * H_SZ + lsrc,
                       (char*)eN + w * 4096 + k * 1024);
        }
    }
    asm volatile("s_waitcnt vmcnt(0)" ::: "memory");   // wave's panels landed

    // ---- fused sLSTM epilogue (LDS panels [64][16] f32 at wave base) -----
    const size_t BH = (size_t)B_SZ * H_SZ;
    const int ebase = w * 1024;                        // float index

#pragma unroll
    for (int mi = 0; mi < 4; ++mi) {
        const int rbase = m0 + wm * 64 + mi * 16 + kq * 4;
        const int erow0 = mi * 16 + kq * 4;            // row within wave panel
#pragma unroll
        for (int r2 = 0; r2 < 4; ++r2) {
            const size_t idx = (size_t)(rbase + r2) * H_SZ + j;
            const int eidx = ebase + (erow0 + r2) * 16 + fr;
            float pi = acc[mi][0][r2] + bvi;
            float pf = acc[mi][1][r2] + bvf;
            float po = acc[mi][2][r2] + bvo;
            float pz = acc[mi][3][r2] + bvz;
            float iv = __expf(pi);
            float fv = rcp_fast(1.0f + __expf(-pf));                   // sigmoid
            float ov = rcp_fast(1.0f + __expf(-po));                   // sigmoid
            float zv = 1.0f - 2.0f * rcp_fast(__expf(2.0f * pz) + 1.0f); // tanh
            float cv = fv * eC[eidx] + iv * zv;
            float nv = fv * eN[eidx] + iv;
            float mv = fmaxf(__logf(fv) + eM[eidx], pi);
            out[idx]          = ov * cv * rcp_fast(nv);                // h
            out[BH + idx]     = cv;                                    // c
            out[3 * BH + idx] = nv;                                    // n
            out[4 * BH + idx] = mv;                                    // m
        }
    }
}

// ---------------------------------------------------------------------------
extern "C" void kernel_launch(void* const* d_in, const int* in_sizes, int n_in,
                              void* d_out, int out_size, void* d_ws, size_t ws_size,
                              hipStream_t stream) {
    const float* x      = (const float*)d_in[0];
    const float* h_prev = (const float*)d_in[1];
    const float* c_prev = (const float*)d_in[2];
    const float* C_prev = (const float*)d_in[3];
    const float* n_prev = (const float*)d_in[4];
    const float* m_prev = (const float*)d_in[5];
    const float* Wz = (const float*)d_in[6];
    const float* bz = (const float*)d_in[7];
    const float* Rz = (const float*)d_in[8];
    const float* Wi = (const float*)d_in[9];
    const float* bi = (const float*)d_in[10];
    const float* Ri = (const float*)d_in[11];
    const float* Wf = (const float*)d_in[12];
    const float* bf = (const float*)d_in[13];
    const float* Rf = (const float*)d_in[14];
    const float* Wo = (const float*)d_in[15];
    const float* bo = (const float*)d_in[16];
    const float* Ro = (const float*)d_in[17];
    float* out = (float*)d_out;

    const size_t BH = (size_t)B_SZ * H_SZ;

    // workspace layout: A_f16 (32MB) | W_f16 (16MB)
    u16* Abuf = (u16*)d_ws;
    u16* Wbuf = (u16*)((char*)d_ws + (size_t)32 * 1024 * 1024);

    convert_AW<<<2048, 256, 0, stream>>>(x, h_prev, Wi, Wf, Wo, Wz,
                                         Ri, Rf, Ro, Rz, C_prev,
                                         Abuf, Wbuf, out + 2 * BH);

    gemm_fused<<<dim3(B_SZ / 128, N4H / 128), 256, 0, stream>>>(
        Abuf, Wbuf, c_prev, n_prev, m_prev, bi, bf, bo, bz, out);
}